// Round 11
// baseline (75.930 us; speedup 1.0000x reference)
//
#include <hip/hip_runtime.h>
#include <hip/hip_bf16.h>

#define NQ     8
#define SEQL   128
#define BATCHN 256
#define EMBED  512
#define DIN    520          // EMBED + NQ
#define NROWS  (SEQL*BATCHN) // 32768
#define GSTR   32           // 4 gates * 8 qubits
#define INV2PI 0.15915494309189535f
#define WROW   524          // Wlds padded row (shorts)

typedef __attribute__((ext_vector_type(8))) short  bf16x8;
typedef __attribute__((ext_vector_type(4))) float  f32x4;
typedef unsigned int uint2v __attribute__((ext_vector_type(2)));

__device__ __forceinline__ short f2bf(float f) {
    union { __hip_bfloat16 h; short s; } u;
    u.h = __float2bfloat16(f);          // RNE convert
    return u.s;
}

// ---------------------------------------------------------------------------
// DPP helpers: row_shr:N -> lane i gets i-N ; row_shl:N -> i+N ;
//              row_ror:8 -> lane i gets i^8 within its 16-lane row
// ---------------------------------------------------------------------------
#define DPP_QP(a,b,c,d) ((a)|((b)<<2)|((c)<<4)|((d)<<6))
#define DPP_SHL(n) (0x100+(n))
#define DPP_SHR(n) (0x110+(n))
#define DPP_ROR(n) (0x120+(n))

template<int CTRL>
__device__ __forceinline__ float updpf(float old_, float src) {
    return __int_as_float(__builtin_amdgcn_update_dpp(
        __float_as_int(old_), __float_as_int(src), CTRL, 0xF, 0xF, false));
}

// value at lane^16 (XOR-extract, semantics-proof)
__device__ __forceinline__ float xor16f(float x) {
    unsigned xu = (unsigned)__float_as_int(x);
    uint2v r = __builtin_amdgcn_permlane16_swap(xu, xu, false, false);
    return __int_as_float((int)(r.x ^ r.y ^ xu));
}

__device__ __forceinline__ float frcp(float x) { return __builtin_amdgcn_rcpf(x); }
__device__ __forceinline__ float fexp2(float x) { return __builtin_amdgcn_exp2f(x); }

#define LOG2E  1.4426950408889634f
#define LOG2E2 2.8853900817779268f

// one LSTM step (r8-proven math), parameterized state: H[8], c, h
#define QSTEP(GV, H, c_own, h_own) do {                                       \
    float sA = fmaf(H[0],Whp[0],fmaf(H[1],Whp[1],fmaf(H[2],Whp[2],H[3]*Whp[3]))); \
    float sB = fmaf(H[4],Whp[4],fmaf(H[5],Whp[5],fmaf(H[6],Whp[6],H[7]*Whp[7]))); \
    float cs = __builtin_amdgcn_cosf((GV) + sA + sB);                         \
    float p = cs, s;                                                          \
    s = updpf<DPP_SHR(1)>(1.0f, p); p *= (m1 ? s : 1.0f);                     \
    s = updpf<DPP_SHR(2)>(1.0f, p); p *= (m2 ? s : 1.0f);                     \
    s = updpf<DPP_SHR(4)>(1.0f, p); p *= (m4 ? s : 1.0f);                     \
    float v = jz ? 1.0f : cs;                                                 \
    v *= updpf<DPP_QP(1,0,3,2)>(v, v);                                        \
    v *= updpf<DPP_QP(2,3,0,1)>(v, v);                                        \
    float xl = updpf<DPP_SHL(4)>(v, v);                                       \
    float xr = updpf<DPP_SHR(4)>(v, v);                                       \
    v *= (m4 ? xr : xl);                                                      \
    float qv = jz ? v : p;                                                    \
    float act = fmaf(sk, frcp(1.0f + fexp2(ek * qv)), ok);                    \
    float A_  = act;                                                          \
    float B8  = updpf<DPP_ROR(8)>(A_, A_);                                    \
    float C16 = xor16f(A_);                                                   \
    float D24 = updpf<DPP_ROR(8)>(C16, C16);                                  \
    float fv = (g==0) ? A_ : (g==1) ? B8 : (g==2) ? C16 : D24;                \
    float iv = (g==1) ? A_ : (g==0) ? B8 : (g==3) ? C16 : D24;                \
    float uv = (g==2) ? A_ : (g==3) ? B8 : (g==0) ? C16 : D24;                \
    float ov = (g==3) ? A_ : (g==2) ? B8 : (g==1) ? C16 : D24;                \
    c_own = fmaf(fv, c_own, iv * uv);                                         \
    float tc = fmaf(-2.0f, frcp(1.0f + fexp2(LOG2E2 * c_own)), 1.0f);         \
    h_own = ov * tc;                                                          \
    H[0] = h_own;                                                             \
    H[1] = updpf<DPP_QP(1,0,3,2)>(H[0], H[0]);                                \
    H[2] = updpf<DPP_QP(2,3,0,1)>(H[0], H[0]);                                \
    H[3] = updpf<DPP_QP(2,3,0,1)>(H[1], H[1]);                                \
    _Pragma("unroll")                                                         \
    for (int rr = 0; rr < 4; ++rr) {                                          \
        float yl = updpf<DPP_SHL(4)>(H[rr], H[rr]);                           \
        float yr = updpf<DPP_SHR(4)>(H[rr], H[rr]);                           \
        H[4 + rr] = m4 ? yr : yl;                                             \
    }                                                                         \
} while (0)

// ---------------------------------------------------------------------------
// Kernel 1 (MFMA, r8-proven verbatim):
//   G[row*32+c] = (emb[sent[row]].W_c + b_c + th_c) * INV2PI
// ---------------------------------------------------------------------------
__global__ __launch_bounds__(256)
void k1_gates(const int* __restrict__ sent, const float* __restrict__ emb,
              const float* __restrict__ Wf, const float* __restrict__ Wi,
              const float* __restrict__ Wu, const float* __restrict__ Wo,
              const float* __restrict__ bf, const float* __restrict__ bi,
              const float* __restrict__ bu, const float* __restrict__ bo,
              const float* __restrict__ thf, const float* __restrict__ thi,
              const float* __restrict__ thu, const float* __restrict__ tho,
              float* __restrict__ G)
{
    __shared__ short Wlds[32][WROW];     // 33.5 KB bf16, [c][k]

    const int tid  = threadIdx.x;
    const int row0 = blockIdx.x * 64;

    // ---- stage W -> bf16 LDS: c = tid&31, segment = tid>>5 (64 floats) ----
    {
        const int c = tid & 31, seg = tid >> 5;
        const int g = c >> 3, j = c & 7;
        const float* W = (g==0) ? Wf : (g==1) ? Wi : (g==2) ? Wu : Wo;
        const float* src = W + (size_t)j * DIN + seg * 64;
        #pragma unroll
        for (int p = 0; p < 8; ++p) {
            float4 u = *reinterpret_cast<const float4*>(src + p * 8);
            float4 v = *reinterpret_cast<const float4*>(src + p * 8 + 4);
            bf16x8 pk;
            pk[0]=f2bf(u.x); pk[1]=f2bf(u.y); pk[2]=f2bf(u.z); pk[3]=f2bf(u.w);
            pk[4]=f2bf(v.x); pk[5]=f2bf(v.y); pk[6]=f2bf(v.z); pk[7]=f2bf(v.w);
            *reinterpret_cast<bf16x8*>(&Wlds[c][seg * 64 + p * 8]) = pk;
        }
    }

    const int l  = tid & 63;             // lane
    const int w  = tid >> 6;             // wave -> M-tile
    const int lm = l & 15;               // row-in-tile / col-in-tile
    const int q  = l >> 4;               // k-quarter (8 elems)

    const int    mytok = sent[row0 + w * 16 + lm];
    const float* arow  = emb + (size_t)mytok * EMBED;

    // bias/theta for the two N-tiles (c = n*16 + lm)
    float bc[2];
    #pragma unroll
    for (int n = 0; n < 2; ++n) {
        int c = n * 16 + lm;
        int g = c >> 3, j = c & 7;
        const float* B  = (g==0) ? bf  : (g==1) ? bi  : (g==2) ? bu  : bo;
        const float* Th = (g==0) ? thf : (g==1) ? thi : (g==2) ? thu : tho;
        bc[n] = (B[j] + Th[j]) * INV2PI;
    }
    __syncthreads();

    f32x4 acc0 = {0.f,0.f,0.f,0.f};
    f32x4 acc1 = {0.f,0.f,0.f,0.f};

    #pragma unroll
    for (int kc = 0; kc < 16; ++kc) {
        const int kl = kc * 32 + q * 8;
        float4 u = *reinterpret_cast<const float4*>(arow + kl);
        float4 v = *reinterpret_cast<const float4*>(arow + kl + 4);
        bf16x8 a;
        a[0]=f2bf(u.x); a[1]=f2bf(u.y); a[2]=f2bf(u.z); a[3]=f2bf(u.w);
        a[4]=f2bf(v.x); a[5]=f2bf(v.y); a[6]=f2bf(v.z); a[7]=f2bf(v.w);
        bf16x8 b0 = *reinterpret_cast<const bf16x8*>(&Wlds[lm][kl]);
        bf16x8 b1 = *reinterpret_cast<const bf16x8*>(&Wlds[16 + lm][kl]);
        acc0 = __builtin_amdgcn_mfma_f32_16x16x32_bf16(a, b0, acc0, 0, 0, 0);
        acc1 = __builtin_amdgcn_mfma_f32_16x16x32_bf16(a, b1, acc1, 0, 0, 0);
    }

    // epilogue: C layout col=lm, row=4*q+r ; scale + fused bias/theta
    #pragma unroll
    for (int r = 0; r < 4; ++r) {
        int row = row0 + w * 16 + q * 4 + r;
        G[(size_t)row * GSTR + 0  + lm] = fmaf(acc0[r], INV2PI, bc[0]);
        G[(size_t)row * GSTR + 16 + lm] = fmaf(acc1[r], INV2PI, bc[1]);
    }
}

// ---------------------------------------------------------------------------
// Kernel 2: LSTM recurrence, r8-proven step math, ILP-2 batch rows per lane.
//   64 blocks x 1 wave. lane32 = g*8+j ; in-wave row rset = tid>>5.
//   Each lane runs TWO independent chains: rows blockIdx*4+rset and +rset+2
//   (weights shared). The second chain's instructions fill the first chain's
//   dependency bubbles (trans-op latency, DPP hazards).
//   G staged to LDS: 4 rows x 128 t x 32 f32 = exactly 64 KB.
// ---------------------------------------------------------------------------
__global__ __launch_bounds__(64)
void k2_lstm(const float* __restrict__ G,
             const float* __restrict__ Wf, const float* __restrict__ Wi,
             const float* __restrict__ Wu, const float* __restrict__ Wo,
             float* __restrict__ out)
{
    __shared__ float gs[SEQL * 128];      // 64 KB: [t][rr*32 + g*8 + j]

    const int tid = threadIdx.x;          // 0..63, 1 wave
    const int l32 = tid & 31;
    const int g   = l32 >> 3;             // gate 0..3 (f,i,u,o)
    const int j   = l32 & 7;              // qubit
    const int rs  = tid >> 5;             // in-wave row-set 0/1
    const int bA  = blockIdx.x * 4 + rs;
    const int bB  = bA + 2;

    // ---- bulk stage this block's G timeline (128 t x 4 rows x 32 f32) ----
    {
        const float* gsrc = G + (size_t)blockIdx.x * 128;
        #pragma unroll 4
        for (int i = 0; i < 64; ++i) {
            int sl = i * 64 + tid;        // float4 slot 0..4095
            int st = sl >> 5, pc = sl & 31;
            float4 v = *reinterpret_cast<const float4*>(
                gsrc + (size_t)st * (BATCHN * GSTR) + pc * 4);
            *reinterpret_cast<float4*>(&gs[sl * 4]) = v;   // sl*4 == st*128+pc*4
        }
    }
    __syncthreads();

    const float* Wsel = (g==0) ? Wf : (g==1) ? Wi : (g==2) ? Wu : Wo;

    // permuted, pre-scaled h-weights (shared by both chains): H[r]=h[j^r]
    float Whp[8];
    #pragma unroll
    for (int rr = 0; rr < 8; ++rr)
        Whp[rr] = Wsel[j * DIN + EMBED + (j ^ rr)] * INV2PI;

    float HA[8], HB[8];
    #pragma unroll
    for (int rr = 0; rr < 8; ++rr) { HA[rr] = 0.f; HB[rr] = 0.f; }
    float cA = 0.f, hA = 0.f, cB = 0.f, hB = 0.f;

    const float* gpA = gs + rs * 32 + l32;        // == gs + tid
    const float* gpB = gpA + 64;                  // rows 2,3
    float nA = gpA[0], nB = gpB[0];

    const bool m1 = (j >= 1), m2 = (j >= 2), m4 = (j >= 4), jz = (j == 0);
    const bool isU = (g == 2);
    const float ek = isU ? LOG2E2 : -LOG2E;
    const float sk = isU ? -2.0f  : 1.0f;
    const float ok = isU ? 1.0f   : 0.0f;

    for (int t = 0; t < SEQL; ++t) {
        // prefetch next step for both chains (off the dependence chain)
        int off = ((t + 1 < SEQL) ? t + 1 : t) * 128;
        float pA = gpA[off], pB = gpB[off];

        QSTEP(nA, HA, cA, hA);        // two independent chains: the compiler
        QSTEP(nB, HB, cB, hB);        // interleaves them to fill stalls

        nA = pA; nB = pB;
    }

    if (l32 < 8) {
        out[bA * NQ + j] = hA;
        out[bB * NQ + j] = hB;
    }
}

// ---------------------------------------------------------------------------
extern "C" void kernel_launch(void* const* d_in, const int* in_sizes, int n_in,
                              void* d_out, int out_size, void* d_ws, size_t ws_size,
                              hipStream_t stream)
{
    const int*   sent = (const int*)  d_in[0];
    // d_in[1] = features : unused by the reference
    const float* emb  = (const float*)d_in[2];
    const float* Wf   = (const float*)d_in[3];
    const float* bf   = (const float*)d_in[4];
    const float* Wi   = (const float*)d_in[5];
    const float* bi   = (const float*)d_in[6];
    const float* Wu   = (const float*)d_in[7];
    const float* bu   = (const float*)d_in[8];
    const float* Wo   = (const float*)d_in[9];
    const float* bo   = (const float*)d_in[10];
    const float* thf  = (const float*)d_in[11];
    const float* thi  = (const float*)d_in[12];
    const float* thu  = (const float*)d_in[13];
    const float* tho  = (const float*)d_in[14];
    float* out = (float*)d_out;

    float* G = (float*)d_ws;   // 32768 * 32 * 4B = 4 MB

    k1_gates<<<NROWS/64, 256, 0, stream>>>(sent, emb, Wf, Wi, Wu, Wo,
                                           bf, bi, bu, bo,
                                           thf, thi, thu, tho, G);
    k2_lstm<<<BATCHN/4, 64, 0, stream>>>(G, Wf, Wi, Wu, Wo, out);
}

// Round 12
// 51.201 us; speedup vs baseline: 1.4830x; 1.4830x over previous
//
#include <hip/hip_runtime.h>
#include <hip/hip_bf16.h>

#define NQ     8
#define SEQL   128
#define BATCHN 256
#define EMBED  512
#define DIN    520          // EMBED + NQ
#define NROWS  (SEQL*BATCHN) // 32768
#define GSTR   32           // 4 gates * 8 qubits
#define INV2PI 0.15915494309189535f
#define WROW   524          // Wlds padded row (shorts)

typedef __attribute__((ext_vector_type(8))) short  bf16x8;
typedef __attribute__((ext_vector_type(4))) float  f32x4;
typedef unsigned int uint2v __attribute__((ext_vector_type(2)));

__device__ __forceinline__ short f2bf(float f) {
    union { __hip_bfloat16 h; short s; } u;
    u.h = __float2bfloat16(f);          // RNE convert
    return u.s;
}

// ---------------------------------------------------------------------------
// DPP helpers: row_shr:N -> lane i gets i-N ; row_shl:N -> i+N ;
//              row_ror:8 -> lane i gets i^8 within its 16-lane row
// ---------------------------------------------------------------------------
#define DPP_QP(a,b,c,d) ((a)|((b)<<2)|((c)<<4)|((d)<<6))
#define DPP_SHL(n) (0x100+(n))
#define DPP_SHR(n) (0x110+(n))
#define DPP_ROR(n) (0x120+(n))

template<int CTRL>
__device__ __forceinline__ float updpf(float old_, float src) {
    return __int_as_float(__builtin_amdgcn_update_dpp(
        __float_as_int(old_), __float_as_int(src), CTRL, 0xF, 0xF, false));
}

// value at lane^16 (XOR-extract, semantics-proof)
__device__ __forceinline__ float xor16f(float x) {
    unsigned xu = (unsigned)__float_as_int(x);
    uint2v r = __builtin_amdgcn_permlane16_swap(xu, xu, false, false);
    return __int_as_float((int)(r.x ^ r.y ^ xu));
}

__device__ __forceinline__ float frcp(float x) { return __builtin_amdgcn_rcpf(x); }
__device__ __forceinline__ float fexp2(float x) { return __builtin_amdgcn_exp2f(x); }

#define LOG2E  1.4426950408889634f
#define LOG2E2 2.8853900817779268f

// ---------------------------------------------------------------------------
// Kernel 1 (MFMA): G[row*32+c] = (emb[sent[row]].W_c + b_c + th_c) * INV2PI
//   r8 structure + DEPTH-8 REGISTER PREFETCH on the A-gather (the 32 global
//   loads were serializing at ~700 cyc each; now 8+ in flight).
//   W staged once to bf16 LDS; fragments as proven (8 consecutive bf16/lane
//   row-major; C: col=lane&15, row=4*(lane>>4)+reg).
// ---------------------------------------------------------------------------
#define K1_COMPUTE(KC, U, V) do {                                             \
    bf16x8 a;                                                                 \
    a[0]=f2bf((U).x); a[1]=f2bf((U).y); a[2]=f2bf((U).z); a[3]=f2bf((U).w);   \
    a[4]=f2bf((V).x); a[5]=f2bf((V).y); a[6]=f2bf((V).z); a[7]=f2bf((V).w);   \
    const int kl_ = (KC) * 32 + q * 8;                                        \
    bf16x8 b0 = *reinterpret_cast<const bf16x8*>(&Wlds[lm][kl_]);             \
    bf16x8 b1 = *reinterpret_cast<const bf16x8*>(&Wlds[16 + lm][kl_]);        \
    acc0 = __builtin_amdgcn_mfma_f32_16x16x32_bf16(a, b0, acc0, 0, 0, 0);     \
    acc1 = __builtin_amdgcn_mfma_f32_16x16x32_bf16(a, b1, acc1, 0, 0, 0);     \
} while (0)

__global__ __launch_bounds__(256, 2)
void k1_gates(const int* __restrict__ sent, const float* __restrict__ emb,
              const float* __restrict__ Wf, const float* __restrict__ Wi,
              const float* __restrict__ Wu, const float* __restrict__ Wo,
              const float* __restrict__ bf, const float* __restrict__ bi,
              const float* __restrict__ bu, const float* __restrict__ bo,
              const float* __restrict__ thf, const float* __restrict__ thi,
              const float* __restrict__ thu, const float* __restrict__ tho,
              float* __restrict__ G)
{
    __shared__ short Wlds[32][WROW];     // 33.5 KB bf16, [c][k]

    const int tid  = threadIdx.x;
    const int row0 = blockIdx.x * 64;

    // ---- stage W -> bf16 LDS: c = tid&31, segment = tid>>5 (64 floats) ----
    {
        const int c = tid & 31, seg = tid >> 5;
        const int g = c >> 3, j = c & 7;
        const float* W = (g==0) ? Wf : (g==1) ? Wi : (g==2) ? Wu : Wo;
        const float* src = W + (size_t)j * DIN + seg * 64;
        #pragma unroll
        for (int p = 0; p < 8; ++p) {
            float4 u = *reinterpret_cast<const float4*>(src + p * 8);
            float4 v = *reinterpret_cast<const float4*>(src + p * 8 + 4);
            bf16x8 pk;
            pk[0]=f2bf(u.x); pk[1]=f2bf(u.y); pk[2]=f2bf(u.z); pk[3]=f2bf(u.w);
            pk[4]=f2bf(v.x); pk[5]=f2bf(v.y); pk[6]=f2bf(v.z); pk[7]=f2bf(v.w);
            *reinterpret_cast<bf16x8*>(&Wlds[c][seg * 64 + p * 8]) = pk;
        }
    }

    const int l  = tid & 63;             // lane
    const int w  = tid >> 6;             // wave -> M-tile
    const int lm = l & 15;               // row-in-tile / col-in-tile
    const int q  = l >> 4;               // k-quarter (8 elems)

    const int    mytok = sent[row0 + w * 16 + lm];
    const float* arow  = emb + (size_t)mytok * EMBED;

    // bias/theta for the two N-tiles (c = n*16 + lm)
    float bc[2];
    #pragma unroll
    for (int n = 0; n < 2; ++n) {
        int c = n * 16 + lm;
        int g = c >> 3, j = c & 7;
        const float* B  = (g==0) ? bf  : (g==1) ? bi  : (g==2) ? bu  : bo;
        const float* Th = (g==0) ? thf : (g==1) ? thi : (g==2) ? thu : tho;
        bc[n] = (B[j] + Th[j]) * INV2PI;
    }
    __syncthreads();

    f32x4 acc0 = {0.f,0.f,0.f,0.f};
    f32x4 acc1 = {0.f,0.f,0.f,0.f};

    // ---- depth-8 register prefetch pipeline over the 16 k-chunks ----
    float4 ua[8], va[8], ub[8], vb[8];
    #pragma unroll
    for (int kc = 0; kc < 8; ++kc) {         // issue first 8 iters' loads
        ua[kc] = *reinterpret_cast<const float4*>(arow + kc * 32 + q * 8);
        va[kc] = *reinterpret_cast<const float4*>(arow + kc * 32 + q * 8 + 4);
    }
    #pragma unroll
    for (int kc = 0; kc < 8; ++kc) {         // issue second half, compute first
        ub[kc] = *reinterpret_cast<const float4*>(arow + (kc + 8) * 32 + q * 8);
        vb[kc] = *reinterpret_cast<const float4*>(arow + (kc + 8) * 32 + q * 8 + 4);
        K1_COMPUTE(kc, ua[kc], va[kc]);
    }
    #pragma unroll
    for (int kc = 0; kc < 8; ++kc) {         // compute second half
        K1_COMPUTE(kc + 8, ub[kc], vb[kc]);
    }

    // epilogue: C layout col=lm, row=4*q+r ; scale + fused bias/theta
    #pragma unroll
    for (int r = 0; r < 4; ++r) {
        int row = row0 + w * 16 + q * 4 + r;
        G[(size_t)row * GSTR + 0  + lm] = fmaf(acc0[r], INV2PI, bc[0]);
        G[(size_t)row * GSTR + 16 + lm] = fmaf(acc1[r], INV2PI, bc[1]);
    }
}

// ---------------------------------------------------------------------------
// Kernel 2: LSTM recurrence (r8-proven, verbatim). 32 lanes/row, 2 rows/wave,
//   128 blocks. All cross-lane on VALU; exp2+rcp activations; LDS-staged G.
// ---------------------------------------------------------------------------
__global__ __launch_bounds__(64)
void k2_lstm(const float* __restrict__ G,
             const float* __restrict__ Wf, const float* __restrict__ Wi,
             const float* __restrict__ Wu, const float* __restrict__ Wo,
             float* __restrict__ out)
{
    __shared__ float gs[SEQL * 64];       // 32 KB: [t][r*32 + g*8 + j]

    const int tid = threadIdx.x;          // 0..63, 1 wave
    const int l32 = tid & 31;
    const int g   = l32 >> 3;             // gate 0..3 (f,i,u,o)
    const int j   = l32 & 7;              // qubit
    const int r   = tid >> 5;             // row-in-block
    const int b   = blockIdx.x * 2 + r;

    // ---- bulk stage this block's G timeline (128 t x 2 rows x 32 f32) ----
    {
        const float* gsrc = G + (size_t)blockIdx.x * 64;
        #pragma unroll 4
        for (int i = 0; i < 32; ++i) {
            int sl = i * 64 + tid;        // float4 slot 0..2047
            int st = sl >> 4, pc = sl & 15;
            float4 v = *reinterpret_cast<const float4*>(
                gsrc + (size_t)st * (BATCHN * GSTR) + pc * 4);
            *reinterpret_cast<float4*>(&gs[sl * 4]) = v;
        }
    }
    __syncthreads();

    const float* Wsel = (g==0) ? Wf : (g==1) ? Wi : (g==2) ? Wu : Wo;

    // permuted, pre-scaled h-weights: dot = sum_r H[r]*Whp[r], H[r]=h[j^r]
    float Whp[8];
    #pragma unroll
    for (int rr = 0; rr < 8; ++rr)
        Whp[rr] = Wsel[j * DIN + EMBED + (j ^ rr)] * INV2PI;

    float H[8];
    #pragma unroll
    for (int rr = 0; rr < 8; ++rr) H[rr] = 0.f;
    float c_own = 0.f, h_own = 0.f;

    const float* gp = gs + tid;           // t*64 + r*32 + l32 == t*64 + tid
    float n = gp[0];

    const bool m1 = (j >= 1), m2 = (j >= 2), m4 = (j >= 4), jz = (j == 0);
    const bool isU = (g == 2);
    const float ek = isU ? LOG2E2 : -LOG2E;
    const float sk = isU ? -2.0f  : 1.0f;
    const float ok = isU ? 1.0f   : 0.0f;

    for (int t = 0; t < SEQL; ++t) {
        // prefetch next step's value from LDS (off the dependence chain)
        float nn = gp[((t + 1 < SEQL) ? t + 1 : t) * 64];

        // a (revolutions) = G + h-dot (split 2x4 chains)
        float sA = fmaf(H[0], Whp[0], fmaf(H[1], Whp[1],
                    fmaf(H[2], Whp[2], H[3] * Whp[3])));
        float sB = fmaf(H[4], Whp[4], fmaf(H[5], Whp[5],
                    fmaf(H[6], Whp[6], H[7] * Whp[7])));
        float cs = __builtin_amdgcn_cosf(n + sA + sB);

        // inclusive prefix product over qubit group (row_shr, guarded)
        float p = cs, s;
        s = updpf<DPP_SHR(1)>(1.0f, p); p *= (m1 ? s : 1.0f);
        s = updpf<DPP_SHR(2)>(1.0f, p); p *= (m2 ? s : 1.0f);
        s = updpf<DPP_SHR(4)>(1.0f, p); p *= (m4 ? s : 1.0f);
        // product of cs_1..cs_7 (butterfly; lane j=0 contributes 1)
        float v = jz ? 1.0f : cs;
        v *= updpf<DPP_QP(1,0,3,2)>(v, v);
        v *= updpf<DPP_QP(2,3,0,1)>(v, v);
        float xl = updpf<DPP_SHL(4)>(v, v);
        float xr = updpf<DPP_SHR(4)>(v, v);
        v *= (m4 ? xr : xl);
        float qv = jz ? v : p;

        // activation (branchless, exp2+rcp)
        float act = fmaf(sk, frcp(1.0f + fexp2(ek * qv)), ok);

        // gate gather, all-VALU: lane^8 = ror8, lane^16 = permlane16_swap,
        // lane^24 = ror8 of that. Gate bits = lane bits 3,4.
        float A   = act;
        float B8  = updpf<DPP_ROR(8)>(A, A);
        float C16 = xor16f(A);
        float D24 = updpf<DPP_ROR(8)>(C16, C16);
        float fv = (g==0) ? A : (g==1) ? B8 : (g==2) ? C16 : D24;
        float iv = (g==1) ? A : (g==0) ? B8 : (g==3) ? C16 : D24;
        float uv = (g==2) ? A : (g==3) ? B8 : (g==0) ? C16 : D24;
        float ov = (g==3) ? A : (g==2) ? B8 : (g==1) ? C16 : D24;

        c_own = fmaf(fv, c_own, iv * uv); // |c| <= 2.07
        float tc = fmaf(-2.0f, frcp(1.0f + fexp2(LOG2E2 * c_own)), 1.0f);
        h_own = ov * tc;

        // all-gather h across the 8-lane qubit group: H[r] = h[j^r]
        H[0] = h_own;
        H[1] = updpf<DPP_QP(1,0,3,2)>(H[0], H[0]);
        H[2] = updpf<DPP_QP(2,3,0,1)>(H[0], H[0]);
        H[3] = updpf<DPP_QP(2,3,0,1)>(H[1], H[1]);
        #pragma unroll
        for (int rr = 0; rr < 4; ++rr) {
            float yl = updpf<DPP_SHL(4)>(H[rr], H[rr]);
            float yr = updpf<DPP_SHR(4)>(H[rr], H[rr]);
            H[4 + rr] = m4 ? yr : yl;
        }

        n = nn;
    }

    if (l32 < 8) out[b * NQ + j] = h_own;
}

// ---------------------------------------------------------------------------
extern "C" void kernel_launch(void* const* d_in, const int* in_sizes, int n_in,
                              void* d_out, int out_size, void* d_ws, size_t ws_size,
                              hipStream_t stream)
{
    const int*   sent = (const int*)  d_in[0];
    // d_in[1] = features : unused by the reference
    const float* emb  = (const float*)d_in[2];
    const float* Wf   = (const float*)d_in[3];
    const float* bf   = (const float*)d_in[4];
    const float* Wi   = (const float*)d_in[5];
    const float* bi   = (const float*)d_in[6];
    const float* Wu   = (const float*)d_in[7];
    const float* bu   = (const float*)d_in[8];
    const float* Wo   = (const float*)d_in[9];
    const float* bo   = (const float*)d_in[10];
    const float* thf  = (const float*)d_in[11];
    const float* thi  = (const float*)d_in[12];
    const float* thu  = (const float*)d_in[13];
    const float* tho  = (const float*)d_in[14];
    float* out = (float*)d_out;

    float* G = (float*)d_ws;   // 32768 * 32 * 4B = 4 MB

    k1_gates<<<NROWS/64, 256, 0, stream>>>(sent, emb, Wf, Wi, Wu, Wo,
                                           bf, bi, bu, bo,
                                           thf, thi, thu, tho, G);
    k2_lstm<<<BATCHN/2, 64, 0, stream>>>(G, Wf, Wi, Wu, Wo, out);
}